// Round 7
// baseline (418.455 us; speedup 1.0000x reference)
//
#include <hip/hip_runtime.h>
#include <hip/hip_bf16.h>

typedef __attribute__((ext_vector_type(4))) float f32x4;
typedef __attribute__((ext_vector_type(8))) short s16x8;
typedef __attribute__((ext_vector_type(4))) short s16x4;
typedef unsigned short u16;
typedef unsigned int u32;

// ---------- helpers ----------
__device__ inline u16 f2bf(float f) {
    union { float f; u32 u; } v; v.f = f;
    u32 r = v.u + 0x7FFFu + ((v.u >> 16) & 1u);   // RNE
    return (u16)(r >> 16);
}
__device__ inline float bfbits2f(u32 hi_bits) {   // pass (bits << 16)
    union { u32 u; float f; } v; v.u = hi_bits; return v.f;
}

// ---------- im2col via LDS transpose ----------
// block <-> (n, py); reads 3 contiguous 28KB channel spans (coalesced, 14
// independent float4/thread), stages bf16 in LDS, writes contiguous 6KB per px.
__global__ __launch_bounds__(384) void im2col_t(const float* __restrict__ img,
                                                u16* __restrict__ patches) {
    __shared__ __align__(16) u16 tile[3 * 32 * 224];   // 43008 B
    const int blk = blockIdx.x;            // 0..1791
    const int n = blk / 7, py = blk - n * 7;
    const int t = threadIdx.x;             // 0..383
    const float* base = img + (size_t)n * 3 * 50176 + py * 32 * 224;
#pragma unroll
    for (int i = 0; i < 14; i++) {
        int f = i * 384 + t;               // float4 index 0..5375
        int c = f / 1792, rem = f - c * 1792;
        float4 v = *(const float4*)(base + (size_t)c * 50176 + rem * 4);
        s16x4 o;
        o[0] = (short)f2bf(v.x); o[1] = (short)f2bf(v.y);
        o[2] = (short)f2bf(v.z); o[3] = (short)f2bf(v.w);
        *(s16x4*)(tile + f * 4) = o;       // linear: LDS byte off = f*8
    }
    __syncthreads();
    const int c = t >> 7, u = t & 127;     // c: 0..2, u: 0..127
    const int r = u >> 2, cc = (u & 3) * 8;
    const u16* lsrc = tile + c * 7168 + r * 224;
    u16* gdst = patches + (size_t)(n * 49 + py * 7) * 3072 + c * 1024 + r * 32 + cc;
#pragma unroll
    for (int px = 0; px < 7; px++) {
        s16x8 v = *(const s16x8*)(lsrc + px * 32 + cc);
        *(s16x8*)(gdst + (size_t)px * 3072) = v;   // block writes 6KB contiguous/px
    }
}

// ---------- weight prep: W_patch cvt + w1cat + w2h ----------
__global__ __launch_bounds__(256) void weight_prep(
    const float* __restrict__ W_patch, u16* __restrict__ wpb,
    const float* __restrict__ W1a, const float* __restrict__ W1b,
    u16* __restrict__ w1cat,
    const float* __restrict__ W2, const float* __restrict__ b2,
    const float* __restrict__ Wp, const float* __restrict__ bp,
    const float* __restrict__ Wpv, const float* __restrict__ bpv,
    const float* __restrict__ Wr, const float* __restrict__ br,
    const float* __restrict__ Wrv, const float* __restrict__ brv,
    float* __restrict__ W2h, float* __restrict__ bias7) {
    const int NW = 147456;               // W_patch 8-elem chunks (384*3072/8)
    const int NC = 1024 * 384;           // w1cat scalars
    const int NH = 3591;                 // 512*7 W2h + 7 bias
    const int total = NW + NC + NH;
    for (int idx = blockIdx.x * 256 + threadIdx.x; idx < total; idx += gridDim.x * 256) {
        if (idx < NW) {
            int i = idx * 8;
            s16x8 o;
#pragma unroll
            for (int q = 0; q < 8; q++) o[q] = (short)f2bf(W_patch[i + q]);
            *(s16x8*)(wpb + i) = o;
        } else if (idx < NW + NC) {
            int t = idx - NW;
            int h = t / 384, k = t - h * 384;
            float v = (h < 512) ? W1a[k * 512 + h] : W1b[k * 512 + (h - 512)];
            w1cat[t] = f2bf(v);
        } else {
            int t = idx - NW - NC;
            if (t < 3584) {
                int h = t / 7, kk = t - h * 7;
                float s = 0.f;
                for (int o = 0; o < 256; o++) {
                    float w = (kk < 2) ? Wp[o * 2 + kk]
                            : (kk < 4) ? Wpv[o * 2 + kk - 2]
                            : (kk < 6) ? Wr[o * 2 + kk - 4]
                                       : Wrv[o];
                    s += W2[h * 256 + o] * w;
                }
                W2h[t] = s;
            } else {
                int kk = t - 3584;
                float s = (kk < 2) ? bp[kk] : (kk < 4) ? bpv[kk - 2]
                        : (kk < 6) ? br[kk - 4] : brv[0];
                for (int o = 0; o < 256; o++) {
                    float w = (kk < 2) ? Wp[o * 2 + kk]
                            : (kk < 4) ? Wpv[o * 2 + kk - 2]
                            : (kk < 6) ? Wr[o * 2 + kk - 4]
                                       : Wrv[o];
                    s += b2[o] * w;
                }
                bias7[kk] = s;
            }
        }
    }
}

// ---------- MFMA GEMM: C[M,N] = A[M,K] @ Bt[N,K]^T (+bias[col]), bf16 in/out ----------
// BM x BN tile, BK=64, 4 waves (2x2), 16x16x32 MFMA, global_load_lds width 16.
template<int BM, int BN>
__global__ __launch_bounds__(256) void gemm_bt(const u16* __restrict__ A,
                                               const u16* __restrict__ Bt,
                                               u16* __restrict__ Cb,
                                               const float* __restrict__ bias,
                                               int M, int N, int K) {
    constexpr int MF = BM / 32;          // M fragments per wave
    constexpr int NF = BN / 32;          // N fragments per wave
    __shared__ __align__(16) u16 As[BM * 64];
    __shared__ __align__(16) u16 Bs[BN * 64];
    const int tid = threadIdx.x;
    const int wave = tid >> 6, lane = tid & 63;
    const int wr = wave >> 1, wc = wave & 1;
    const int row0 = blockIdx.x * BM, col0 = blockIdx.y * BN;
    const int lr = lane >> 3;            // 0..7
    const int lcb = (lane & 7) * 8;      // element col within 64-wide K slice
    f32x4 acc[MF][NF] = {};

    for (int k0 = 0; k0 < K; k0 += 64) {
        __syncthreads();                 // protect LDS from prior-iter readers
#pragma unroll
        for (int q = 0; q < BM / 32; q++) {
            int ch = q * 4 + wave;
            const u16* gA = A + (size_t)(row0 + ch * 8 + lr) * K + k0 + lcb;
            __builtin_amdgcn_global_load_lds(
                (const __attribute__((address_space(1))) unsigned int*)gA,
                (__attribute__((address_space(3))) unsigned int*)(As + ch * 512), 16, 0, 0);
        }
#pragma unroll
        for (int q = 0; q < BN / 32; q++) {
            int ch = q * 4 + wave;
            const u16* gB = Bt + (size_t)(col0 + ch * 8 + lr) * K + k0 + lcb;
            __builtin_amdgcn_global_load_lds(
                (const __attribute__((address_space(1))) unsigned int*)gB,
                (__attribute__((address_space(3))) unsigned int*)(Bs + ch * 512), 16, 0, 0);
        }
        __syncthreads();                 // compiler drains vmcnt before barrier
#pragma unroll
        for (int kk = 0; kk < 64; kk += 32) {
            s16x8 af[MF], bfr[NF];
#pragma unroll
            for (int m = 0; m < MF; m++)
                af[m] = *(const s16x8*)(As + (wr * (BM / 2) + m * 16 + (lane & 15)) * 64 + kk + (lane >> 4) * 8);
#pragma unroll
            for (int n = 0; n < NF; n++)
                bfr[n] = *(const s16x8*)(Bs + (wc * (BN / 2) + n * 16 + (lane & 15)) * 64 + kk + (lane >> 4) * 8);
#pragma unroll
            for (int m = 0; m < MF; m++)
#pragma unroll
                for (int n = 0; n < NF; n++)
                    acc[m][n] = __builtin_amdgcn_mfma_f32_16x16x32_bf16(af[m], bfr[n], acc[m][n], 0, 0, 0);
        }
    }
    // epilogue: D row=(lane>>4)*4+i, col=lane&15 (m89-verified layout)
#pragma unroll
    for (int m = 0; m < MF; m++) {
        int drow = row0 + wr * (BM / 2) + m * 16 + (lane >> 4) * 4;
#pragma unroll
        for (int n = 0; n < NF; n++) {
            int dcol = col0 + wc * (BN / 2) + n * 16 + (lane & 15);
            float bv = bias ? bias[dcol] : 0.0f;
#pragma unroll
            for (int i = 0; i < 4; i++)
                Cb[(size_t)(drow + i) * N + dcol] = f2bf(acc[m][n][i] + bv);
        }
    }
}

// ---------- per-edge head computation (+ node_preds zeroing) ----------
// ag: (12544 x 1024) bf16, cols 0..511 = a, 512..1023 = g
__global__ __launch_bounds__(256) void edge_kernel(
    const u16* __restrict__ ag, const float* __restrict__ pos,
    const float* __restrict__ b1, const float* __restrict__ W2h,
    const float* __restrict__ bias7,
    float* __restrict__ edge_out, float* __restrict__ mask_out,
    float* __restrict__ node_preds) {
    __shared__ float red[4][7];
    const int e = blockIdx.x;                // 0..2047
    const int b = e >> 6, ij = e & 63, i = ij >> 3, j = ij & 7;
    const int t = threadIdx.x;
    // zero this block's slice of node_preds (2048 * 450 = 921600)
    for (int z = t; z < 450; z += 256) node_preds[(size_t)e * 450 + z] = 0.0f;
    const float dx = pos[(b * 8 + i) * 3 + 0] - pos[(b * 8 + j) * 3 + 0];
    const float dy = pos[(b * 8 + i) * 3 + 1] - pos[(b * 8 + j) * 3 + 1];
    const bool msk = (dx * dx + dy * dy < 0.25f) && (i != j);
    if (t == 0) mask_out[e] = msk ? 1.0f : 0.0f;
    if (!msk) {                              // block-uniform branch
        if (t < 7) edge_out[e * 7 + t] = 0.0f;
        return;
    }
    const int h0 = t * 2;
    const u16* arow = ag + (size_t)(b * 8 + i) * 49 * 1024 + h0;
    const u16* grow = ag + (size_t)(b * 8 + j) * 49 * 1024 + 512 + h0;
    const float b10 = b1[h0], b11 = b1[h0 + 1];
    float r0 = 0.f, r1 = 0.f;
#pragma unroll 7
    for (int s = 0; s < 49; s++) {
        u32 av = *(const u32*)(arow + (size_t)s * 1024);
        u32 gv = *(const u32*)(grow + (size_t)s * 1024);
        float a0 = bfbits2f(av << 16), a1 = bfbits2f(av & 0xFFFF0000u);
        float g0 = bfbits2f(gv << 16), g1 = bfbits2f(gv & 0xFFFF0000u);
        r0 += fmaxf(a0 + g0 + b10, 0.f);
        r1 += fmaxf(a1 + g1 + b11, 0.f);
    }
    float c[7];
#pragma unroll
    for (int k = 0; k < 7; k++)
        c[k] = r0 * W2h[h0 * 7 + k] + r1 * W2h[(h0 + 1) * 7 + k];
#pragma unroll
    for (int k = 0; k < 7; k++)
#pragma unroll
        for (int off = 32; off; off >>= 1)
            c[k] += __shfl_down(c[k], off, 64);
    const int lane = t & 63, wv = t >> 6;
    if (lane == 0)
        for (int k = 0; k < 7; k++) red[wv][k] = c[k];
    __syncthreads();
    if (t == 0)
        for (int k = 0; k < 7; k++) {
            float v = red[0][k] + red[1][k] + red[2][k] + red[3][k];
            edge_out[e * 7 + k] = v * (1.f / 49.f) + bias7[k];
        }
}

// ---------- launch ----------
extern "C" void kernel_launch(void* const* d_in, const int* in_sizes, int n_in,
                              void* d_out, int out_size, void* d_ws, size_t ws_size,
                              hipStream_t stream) {
    const float* img    = (const float*)d_in[0];
    const float* pos    = (const float*)d_in[1];
    const float* W_patch= (const float*)d_in[3];
    const float* b_patch= (const float*)d_in[4];
    const float* W1a    = (const float*)d_in[5];
    const float* W1b    = (const float*)d_in[6];
    const float* b1     = (const float*)d_in[7];
    const float* W2     = (const float*)d_in[8];
    const float* b2     = (const float*)d_in[9];
    const float* Wp     = (const float*)d_in[10];
    const float* bp     = (const float*)d_in[11];
    const float* Wpv    = (const float*)d_in[12];
    const float* bpv    = (const float*)d_in[13];
    const float* Wr     = (const float*)d_in[14];
    const float* br     = (const float*)d_in[15];
    const float* Wrv    = (const float*)d_in[16];
    const float* brv    = (const float*)d_in[17];

    char* ws = (char*)d_ws;
    u16*   patches = (u16*)(ws + 0);                      // 12544*3072*2 = 77,070,336
    u16*   ag      = (u16*)(ws + 77070336);               // 12544*1024*2 = 25,690,112
    u16*   feats   = (u16*)(ws + 102760448);              // 12544*384*2  =  9,633,792
    u16*   wpb     = (u16*)(ws + 112394240);              // 384*3072*2   =  2,359,296
    u16*   w1cat   = (u16*)(ws + 114753536);              // 1024*384*2   =    786,432
    float* W2h     = (float*)(ws + 115539968);            // 512*7*4      =     14,336
    float* bias7   = (float*)(ws + 115554304);            // 7*4

    float* edge_out   = (float*)d_out;                    // 2048*7
    float* mask_out   = edge_out + 14336;                 // 2048
    float* node_preds = mask_out + 2048;                  // 32*8*3600 = 921,600

    weight_prep<<<2048, 256, 0, stream>>>(W_patch, wpb, W1a, W1b, w1cat,
                                          W2, b2, Wp, bp, Wpv, bpv, Wr, br, Wrv, brv,
                                          W2h, bias7);
    im2col_t<<<1792, 384, 0, stream>>>(img, patches);

    dim3 g1(98, 6);   // BM=128, BN=64 -> 588 blocks (~2.3/CU for barrier-drain overlap)
    gemm_bt<128, 64><<<g1, 256, 0, stream>>>(patches, wpb, feats, b_patch, 12544, 384, 3072);
    dim3 g2(196, 8);  // BM=64, BN=128 -> 1568 blocks (~6/CU, short-K GEMM)
    gemm_bt<64, 128><<<g2, 256, 0, stream>>>(feats, w1cat, ag, nullptr, 12544, 1024, 384);

    edge_kernel<<<2048, 256, 0, stream>>>(ag, pos, b1, W2h, bias7,
                                          edge_out, mask_out, node_preds);
}

// Round 8
// 417.786 us; speedup vs baseline: 1.0016x; 1.0016x over previous
//
#include <hip/hip_runtime.h>
#include <hip/hip_bf16.h>

typedef __attribute__((ext_vector_type(4))) float f32x4;
typedef __attribute__((ext_vector_type(8))) short s16x8;
typedef __attribute__((ext_vector_type(4))) short s16x4;
typedef unsigned short u16;
typedef unsigned int u32;

// ---------- helpers ----------
__device__ inline u16 f2bf(float f) {
    union { float f; u32 u; } v; v.f = f;
    u32 r = v.u + 0x7FFFu + ((v.u >> 16) & 1u);   // RNE
    return (u16)(r >> 16);
}
__device__ inline float bfbits2f(u32 hi_bits) {   // pass (bits << 16)
    union { u32 u; float f; } v; v.u = hi_bits; return v.f;
}

// ---------- merged prep: im2col (blocks 0..1791) + weight prep (blocks 1792..1919) ----------
// im2col via LDS transpose: block <-> (n, py); reads 3 contiguous 28KB channel
// spans (coalesced), stages bf16 in LDS, writes contiguous 6KB per px.
// Weight blocks run grid-stride over W_patch cvt + w1cat + W2h fold.
__global__ __launch_bounds__(384) void prep_all(
    const float* __restrict__ img, u16* __restrict__ patches,
    const float* __restrict__ W_patch, u16* __restrict__ wpb,
    const float* __restrict__ W1a, const float* __restrict__ W1b,
    u16* __restrict__ w1cat,
    const float* __restrict__ W2, const float* __restrict__ b2,
    const float* __restrict__ Wp, const float* __restrict__ bp,
    const float* __restrict__ Wpv, const float* __restrict__ bpv,
    const float* __restrict__ Wr, const float* __restrict__ br,
    const float* __restrict__ Wrv, const float* __restrict__ brv,
    float* __restrict__ W2h, float* __restrict__ bias7) {
    __shared__ __align__(16) u16 tile[3 * 32 * 224];   // 43008 B
    const int blk = blockIdx.x;
    const int t = threadIdx.x;             // 0..383
    if (blk < 1792) {
        // ---- im2col path ----
        const int n = blk / 7, py = blk - n * 7;
        const float* base = img + (size_t)n * 3 * 50176 + py * 32 * 224;
#pragma unroll
        for (int i = 0; i < 14; i++) {
            int f = i * 384 + t;               // float4 index 0..5375
            int c = f / 1792, rem = f - c * 1792;
            float4 v = *(const float4*)(base + (size_t)c * 50176 + rem * 4);
            s16x4 o;
            o[0] = (short)f2bf(v.x); o[1] = (short)f2bf(v.y);
            o[2] = (short)f2bf(v.z); o[3] = (short)f2bf(v.w);
            *(s16x4*)(tile + f * 4) = o;       // linear: LDS byte off = f*8
        }
        __syncthreads();
        const int c = t >> 7, u = t & 127;     // c: 0..2, u: 0..127
        const int r = u >> 2, cc = (u & 3) * 8;
        const u16* lsrc = tile + c * 7168 + r * 224;
        u16* gdst = patches + (size_t)(n * 49 + py * 7) * 3072 + c * 1024 + r * 32 + cc;
#pragma unroll
        for (int px = 0; px < 7; px++) {
            s16x8 v = *(const s16x8*)(lsrc + px * 32 + cc);
            *(s16x8*)(gdst + (size_t)px * 3072) = v;   // block writes 6KB contiguous/px
        }
        return;
    }
    // ---- weight prep path ----
    const int NW = 147456;               // W_patch 8-elem chunks (384*3072/8)
    const int NC = 1024 * 384;           // w1cat scalars
    const int NH = 3591;                 // 512*7 W2h + 7 bias
    const int total = NW + NC + NH;
    for (int idx = (blk - 1792) * 384 + t; idx < total; idx += 128 * 384) {
        if (idx < NW) {
            int i = idx * 8;
            s16x8 o;
#pragma unroll
            for (int q = 0; q < 8; q++) o[q] = (short)f2bf(W_patch[i + q]);
            *(s16x8*)(wpb + i) = o;
        } else if (idx < NW + NC) {
            int w = idx - NW;
            int h = w / 384, k = w - h * 384;
            float v = (h < 512) ? W1a[k * 512 + h] : W1b[k * 512 + (h - 512)];
            w1cat[w] = f2bf(v);
        } else {
            int w = idx - NW - NC;
            if (w < 3584) {
                int h = w / 7, kk = w - h * 7;
                float s = 0.f;
                for (int o = 0; o < 256; o++) {
                    float ww = (kk < 2) ? Wp[o * 2 + kk]
                             : (kk < 4) ? Wpv[o * 2 + kk - 2]
                             : (kk < 6) ? Wr[o * 2 + kk - 4]
                                        : Wrv[o];
                    s += W2[h * 256 + o] * ww;
                }
                W2h[w] = s;
            } else {
                int kk = w - 3584;
                float s = (kk < 2) ? bp[kk] : (kk < 4) ? bpv[kk - 2]
                        : (kk < 6) ? br[kk - 4] : brv[0];
                for (int o = 0; o < 256; o++) {
                    float ww = (kk < 2) ? Wp[o * 2 + kk]
                             : (kk < 4) ? Wpv[o * 2 + kk - 2]
                             : (kk < 6) ? Wr[o * 2 + kk - 4]
                                        : Wrv[o];
                    s += b2[o] * ww;
                }
                bias7[kk] = s;
            }
        }
    }
}

// ---------- MFMA GEMM: C[M,N] = A[M,K] @ Bt[N,K]^T (+bias[col]), bf16 in/out ----------
// BM x BN tile, BK=64, 4 waves (2x2), 16x16x32 MFMA, global_load_lds width 16.
template<int BM, int BN>
__global__ __launch_bounds__(256) void gemm_bt(const u16* __restrict__ A,
                                               const u16* __restrict__ Bt,
                                               u16* __restrict__ Cb,
                                               const float* __restrict__ bias,
                                               int M, int N, int K) {
    constexpr int MF = BM / 32;          // M fragments per wave
    constexpr int NF = BN / 32;          // N fragments per wave
    __shared__ __align__(16) u16 As[BM * 64];
    __shared__ __align__(16) u16 Bs[BN * 64];
    const int tid = threadIdx.x;
    const int wave = tid >> 6, lane = tid & 63;
    const int wr = wave >> 1, wc = wave & 1;
    const int row0 = blockIdx.x * BM, col0 = blockIdx.y * BN;
    const int lr = lane >> 3;            // 0..7
    const int lcb = (lane & 7) * 8;      // element col within 64-wide K slice
    f32x4 acc[MF][NF] = {};

    for (int k0 = 0; k0 < K; k0 += 64) {
        __syncthreads();                 // protect LDS from prior-iter readers
#pragma unroll
        for (int q = 0; q < BM / 32; q++) {
            int ch = q * 4 + wave;
            const u16* gA = A + (size_t)(row0 + ch * 8 + lr) * K + k0 + lcb;
            __builtin_amdgcn_global_load_lds(
                (const __attribute__((address_space(1))) unsigned int*)gA,
                (__attribute__((address_space(3))) unsigned int*)(As + ch * 512), 16, 0, 0);
        }
#pragma unroll
        for (int q = 0; q < BN / 32; q++) {
            int ch = q * 4 + wave;
            const u16* gB = Bt + (size_t)(col0 + ch * 8 + lr) * K + k0 + lcb;
            __builtin_amdgcn_global_load_lds(
                (const __attribute__((address_space(1))) unsigned int*)gB,
                (__attribute__((address_space(3))) unsigned int*)(Bs + ch * 512), 16, 0, 0);
        }
        __syncthreads();                 // compiler drains vmcnt before barrier
#pragma unroll
        for (int kk = 0; kk < 64; kk += 32) {
            s16x8 af[MF], bfr[NF];
#pragma unroll
            for (int m = 0; m < MF; m++)
                af[m] = *(const s16x8*)(As + (wr * (BM / 2) + m * 16 + (lane & 15)) * 64 + kk + (lane >> 4) * 8);
#pragma unroll
            for (int n = 0; n < NF; n++)
                bfr[n] = *(const s16x8*)(Bs + (wc * (BN / 2) + n * 16 + (lane & 15)) * 64 + kk + (lane >> 4) * 8);
#pragma unroll
            for (int m = 0; m < MF; m++)
#pragma unroll
                for (int n = 0; n < NF; n++)
                    acc[m][n] = __builtin_amdgcn_mfma_f32_16x16x32_bf16(af[m], bfr[n], acc[m][n], 0, 0, 0);
        }
    }
    // epilogue: D row=(lane>>4)*4+i, col=lane&15 (m89-verified layout)
#pragma unroll
    for (int m = 0; m < MF; m++) {
        int drow = row0 + wr * (BM / 2) + m * 16 + (lane >> 4) * 4;
#pragma unroll
        for (int n = 0; n < NF; n++) {
            int dcol = col0 + wc * (BN / 2) + n * 16 + (lane & 15);
            float bv = bias ? bias[dcol] : 0.0f;
#pragma unroll
            for (int i = 0; i < 4; i++)
                Cb[(size_t)(drow + i) * N + dcol] = f2bf(acc[m][n][i] + bv);
        }
    }
}

// ---------- per-edge head computation (+ node_preds zeroing) ----------
// ag: (12544 x 1024) bf16, cols 0..511 = a, 512..1023 = g
__global__ __launch_bounds__(256) void edge_kernel(
    const u16* __restrict__ ag, const float* __restrict__ pos,
    const float* __restrict__ b1, const float* __restrict__ W2h,
    const float* __restrict__ bias7,
    float* __restrict__ edge_out, float* __restrict__ mask_out,
    float* __restrict__ node_preds) {
    __shared__ float red[4][7];
    const int e = blockIdx.x;                // 0..2047
    const int b = e >> 6, ij = e & 63, i = ij >> 3, j = ij & 7;
    const int t = threadIdx.x;
    // zero this block's slice of node_preds (2048 * 450 = 921600)
    for (int z = t; z < 450; z += 256) node_preds[(size_t)e * 450 + z] = 0.0f;
    const float dx = pos[(b * 8 + i) * 3 + 0] - pos[(b * 8 + j) * 3 + 0];
    const float dy = pos[(b * 8 + i) * 3 + 1] - pos[(b * 8 + j) * 3 + 1];
    const bool msk = (dx * dx + dy * dy < 0.25f) && (i != j);
    if (t == 0) mask_out[e] = msk ? 1.0f : 0.0f;
    if (!msk) {                              // block-uniform branch
        if (t < 7) edge_out[e * 7 + t] = 0.0f;
        return;
    }
    const int h0 = t * 2;
    const u16* arow = ag + (size_t)(b * 8 + i) * 49 * 1024 + h0;
    const u16* grow = ag + (size_t)(b * 8 + j) * 49 * 1024 + 512 + h0;
    const float b10 = b1[h0], b11 = b1[h0 + 1];
    float r0 = 0.f, r1 = 0.f;
#pragma unroll 7
    for (int s = 0; s < 49; s++) {
        u32 av = *(const u32*)(arow + (size_t)s * 1024);
        u32 gv = *(const u32*)(grow + (size_t)s * 1024);
        float a0 = bfbits2f(av << 16), a1 = bfbits2f(av & 0xFFFF0000u);
        float g0 = bfbits2f(gv << 16), g1 = bfbits2f(gv & 0xFFFF0000u);
        r0 += fmaxf(a0 + g0 + b10, 0.f);
        r1 += fmaxf(a1 + g1 + b11, 0.f);
    }
    float c[7];
#pragma unroll
    for (int k = 0; k < 7; k++)
        c[k] = r0 * W2h[h0 * 7 + k] + r1 * W2h[(h0 + 1) * 7 + k];
#pragma unroll
    for (int k = 0; k < 7; k++)
#pragma unroll
        for (int off = 32; off; off >>= 1)
            c[k] += __shfl_down(c[k], off, 64);
    const int lane = t & 63, wv = t >> 6;
    if (lane == 0)
        for (int k = 0; k < 7; k++) red[wv][k] = c[k];
    __syncthreads();
    if (t == 0)
        for (int k = 0; k < 7; k++) {
            float v = red[0][k] + red[1][k] + red[2][k] + red[3][k];
            edge_out[e * 7 + k] = v * (1.f / 49.f) + bias7[k];
        }
}

// ---------- launch ----------
extern "C" void kernel_launch(void* const* d_in, const int* in_sizes, int n_in,
                              void* d_out, int out_size, void* d_ws, size_t ws_size,
                              hipStream_t stream) {
    const float* img    = (const float*)d_in[0];
    const float* pos    = (const float*)d_in[1];
    const float* W_patch= (const float*)d_in[3];
    const float* b_patch= (const float*)d_in[4];
    const float* W1a    = (const float*)d_in[5];
    const float* W1b    = (const float*)d_in[6];
    const float* b1     = (const float*)d_in[7];
    const float* W2     = (const float*)d_in[8];
    const float* b2     = (const float*)d_in[9];
    const float* Wp     = (const float*)d_in[10];
    const float* bp     = (const float*)d_in[11];
    const float* Wpv    = (const float*)d_in[12];
    const float* bpv    = (const float*)d_in[13];
    const float* Wr     = (const float*)d_in[14];
    const float* br     = (const float*)d_in[15];
    const float* Wrv    = (const float*)d_in[16];
    const float* brv    = (const float*)d_in[17];

    char* ws = (char*)d_ws;
    u16*   patches = (u16*)(ws + 0);                      // 12544*3072*2 = 77,070,336
    u16*   ag      = (u16*)(ws + 77070336);               // 12544*1024*2 = 25,690,112
    u16*   feats   = (u16*)(ws + 102760448);              // 12544*384*2  =  9,633,792
    u16*   wpb     = (u16*)(ws + 112394240);              // 384*3072*2   =  2,359,296
    u16*   w1cat   = (u16*)(ws + 114753536);              // 1024*384*2   =    786,432
    float* W2h     = (float*)(ws + 115539968);            // 512*7*4      =     14,336
    float* bias7   = (float*)(ws + 115554304);            // 7*4

    float* edge_out   = (float*)d_out;                    // 2048*7
    float* mask_out   = edge_out + 14336;                 // 2048
    float* node_preds = mask_out + 2048;                  // 32*8*3600 = 921,600

    prep_all<<<1920, 384, 0, stream>>>(img, patches, W_patch, wpb,
                                       W1a, W1b, w1cat,
                                       W2, b2, Wp, bp, Wpv, bpv, Wr, br, Wrv, brv,
                                       W2h, bias7);

    dim3 g1(98, 6);   // BM=128, BN=64 -> 588 blocks (~2.3/CU for barrier-drain overlap)
    gemm_bt<128, 64><<<g1, 256, 0, stream>>>(patches, wpb, feats, b_patch, 12544, 384, 3072);
    dim3 g2(196, 8);  // BM=64, BN=128 -> 1568 blocks (~6/CU, short-K GEMM)
    gemm_bt<64, 128><<<g2, 256, 0, stream>>>(feats, w1cat, ag, nullptr, 12544, 1024, 384);

    edge_kernel<<<2048, 256, 0, stream>>>(ag, pos, b1, W2h, bias7,
                                          edge_out, mask_out, node_preds);
}

// Round 9
// 403.922 us; speedup vs baseline: 1.0360x; 1.0343x over previous
//
#include <hip/hip_runtime.h>
#include <hip/hip_bf16.h>

typedef __attribute__((ext_vector_type(4))) float f32x4;
typedef __attribute__((ext_vector_type(8))) short s16x8;
typedef unsigned short u16;
typedef unsigned int u32;

// ---------- helpers ----------
__device__ inline u16 f2bf(float f) {
    union { float f; u32 u; } v; v.f = f;
    u32 r = v.u + 0x7FFFu + ((v.u >> 16) & 1u);   // RNE
    return (u16)(r >> 16);
}
__device__ inline float bfbits2f(u32 hi_bits) {   // pass (bits << 16)
    union { u32 u; float f; } v; v.u = hi_bits; return v.f;
}

// ---------- merged prep, no LDS, batched loads for MLP ----------
// blocks 0..4703: im2col, 4 chunks/thread, all 8 float4 loads issued before
// converts (independent -> deep MLP). blocks 4704..4831: weight prep.
#define IMB 4704
__global__ __launch_bounds__(256) void prep_fast(
    const float* __restrict__ img, u16* __restrict__ patches,
    const float* __restrict__ W_patch, u16* __restrict__ wpb,
    const float* __restrict__ W1a, const float* __restrict__ W1b,
    u16* __restrict__ w1cat,
    const float* __restrict__ W2, const float* __restrict__ b2,
    const float* __restrict__ Wp, const float* __restrict__ bp,
    const float* __restrict__ Wpv, const float* __restrict__ bpv,
    const float* __restrict__ Wr, const float* __restrict__ br,
    const float* __restrict__ Wrv, const float* __restrict__ brv,
    float* __restrict__ W2h, float* __restrict__ bias7) {
    const int blk = blockIdx.x;
    const int t = threadIdx.x;
    if (blk < IMB) {
        // ---- im2col: chunks blk*1024 + s*256 + t, s=0..3 ----
        const int base = blk * 1024 + t;
        float4 va[4], vb[4];
#pragma unroll
        for (int s = 0; s < 4; s++) {
            int cid = base + s * 256;
            int m = cid / 384;
            int kc = cid - m * 384;
            int k = kc * 8;
            int c = k >> 10;
            int rem = k & 1023;
            int r = rem >> 5;
            int cc = rem & 31;
            int n = m / 49;
            int ss = m - n * 49;
            int py = ss / 7;
            int px = ss - py * 7;
            const float* src = img + (((size_t)(n * 3 + c) * 224 + py * 32 + r) * 224 + px * 32 + cc);
            va[s] = *(const float4*)src;
            vb[s] = *(const float4*)(src + 4);
        }
#pragma unroll
        for (int s = 0; s < 4; s++) {
            s16x8 o;
            o[0] = (short)f2bf(va[s].x); o[1] = (short)f2bf(va[s].y);
            o[2] = (short)f2bf(va[s].z); o[3] = (short)f2bf(va[s].w);
            o[4] = (short)f2bf(vb[s].x); o[5] = (short)f2bf(vb[s].y);
            o[6] = (short)f2bf(vb[s].z); o[7] = (short)f2bf(vb[s].w);
            *(s16x8*)(patches + (size_t)(base + s * 256) * 8) = o;
        }
        return;
    }
    // ---- weight prep path ----
    const int NW = 147456;               // W_patch 8-elem chunks (384*3072/8)
    const int NC = 1024 * 384;           // w1cat scalars
    const int NH = 3591;                 // 512*7 W2h + 7 bias
    const int total = NW + NC + NH;
    for (int idx = (blk - IMB) * 256 + t; idx < total; idx += 128 * 256) {
        if (idx < NW) {
            int i = idx * 8;
            s16x8 o;
#pragma unroll
            for (int q = 0; q < 8; q++) o[q] = (short)f2bf(W_patch[i + q]);
            *(s16x8*)(wpb + i) = o;
        } else if (idx < NW + NC) {
            int w = idx - NW;
            int h = w / 384, k = w - h * 384;
            float v = (h < 512) ? W1a[k * 512 + h] : W1b[k * 512 + (h - 512)];
            w1cat[w] = f2bf(v);
        } else {
            int w = idx - NW - NC;
            if (w < 3584) {
                int h = w / 7, kk = w - h * 7;
                float s = 0.f;
                for (int o = 0; o < 256; o++) {
                    float ww = (kk < 2) ? Wp[o * 2 + kk]
                             : (kk < 4) ? Wpv[o * 2 + kk - 2]
                             : (kk < 6) ? Wr[o * 2 + kk - 4]
                                        : Wrv[o];
                    s += W2[h * 256 + o] * ww;
                }
                W2h[w] = s;
            } else {
                int kk = w - 3584;
                float s = (kk < 2) ? bp[kk] : (kk < 4) ? bpv[kk - 2]
                        : (kk < 6) ? br[kk - 4] : brv[0];
                for (int o = 0; o < 256; o++) {
                    float ww = (kk < 2) ? Wp[o * 2 + kk]
                             : (kk < 4) ? Wpv[o * 2 + kk - 2]
                             : (kk < 6) ? Wr[o * 2 + kk - 4]
                                        : Wrv[o];
                    s += b2[o] * ww;
                }
                bias7[kk] = s;
            }
        }
    }
}

// ---------- MFMA GEMM: C[M,N] = A[M,K] @ Bt[N,K]^T (+bias[col]), bf16 in/out ----------
// BM x BN tile, BK=64, 4 waves (2x2), 16x16x32 MFMA, global_load_lds width 16.
template<int BM, int BN>
__global__ __launch_bounds__(256) void gemm_bt(const u16* __restrict__ A,
                                               const u16* __restrict__ Bt,
                                               u16* __restrict__ Cb,
                                               const float* __restrict__ bias,
                                               int M, int N, int K) {
    constexpr int MF = BM / 32;          // M fragments per wave
    constexpr int NF = BN / 32;          // N fragments per wave
    __shared__ __align__(16) u16 As[BM * 64];
    __shared__ __align__(16) u16 Bs[BN * 64];
    const int tid = threadIdx.x;
    const int wave = tid >> 6, lane = tid & 63;
    const int wr = wave >> 1, wc = wave & 1;
    const int row0 = blockIdx.x * BM, col0 = blockIdx.y * BN;
    const int lr = lane >> 3;            // 0..7
    const int lcb = (lane & 7) * 8;      // element col within 64-wide K slice
    f32x4 acc[MF][NF] = {};

    for (int k0 = 0; k0 < K; k0 += 64) {
        __syncthreads();                 // protect LDS from prior-iter readers
#pragma unroll
        for (int q = 0; q < BM / 32; q++) {
            int ch = q * 4 + wave;
            const u16* gA = A + (size_t)(row0 + ch * 8 + lr) * K + k0 + lcb;
            __builtin_amdgcn_global_load_lds(
                (const __attribute__((address_space(1))) unsigned int*)gA,
                (__attribute__((address_space(3))) unsigned int*)(As + ch * 512), 16, 0, 0);
        }
#pragma unroll
        for (int q = 0; q < BN / 32; q++) {
            int ch = q * 4 + wave;
            const u16* gB = Bt + (size_t)(col0 + ch * 8 + lr) * K + k0 + lcb;
            __builtin_amdgcn_global_load_lds(
                (const __attribute__((address_space(1))) unsigned int*)gB,
                (__attribute__((address_space(3))) unsigned int*)(Bs + ch * 512), 16, 0, 0);
        }
        __syncthreads();                 // compiler drains vmcnt before barrier
#pragma unroll
        for (int kk = 0; kk < 64; kk += 32) {
            s16x8 af[MF], bfr[NF];
#pragma unroll
            for (int m = 0; m < MF; m++)
                af[m] = *(const s16x8*)(As + (wr * (BM / 2) + m * 16 + (lane & 15)) * 64 + kk + (lane >> 4) * 8);
#pragma unroll
            for (int n = 0; n < NF; n++)
                bfr[n] = *(const s16x8*)(Bs + (wc * (BN / 2) + n * 16 + (lane & 15)) * 64 + kk + (lane >> 4) * 8);
#pragma unroll
            for (int m = 0; m < MF; m++)
#pragma unroll
                for (int n = 0; n < NF; n++)
                    acc[m][n] = __builtin_amdgcn_mfma_f32_16x16x32_bf16(af[m], bfr[n], acc[m][n], 0, 0, 0);
        }
    }
    // epilogue: D row=(lane>>4)*4+i, col=lane&15 (m89-verified layout)
#pragma unroll
    for (int m = 0; m < MF; m++) {
        int drow = row0 + wr * (BM / 2) + m * 16 + (lane >> 4) * 4;
#pragma unroll
        for (int n = 0; n < NF; n++) {
            int dcol = col0 + wc * (BN / 2) + n * 16 + (lane & 15);
            float bv = bias ? bias[dcol] : 0.0f;
#pragma unroll
            for (int i = 0; i < 4; i++)
                Cb[(size_t)(drow + i) * N + dcol] = f2bf(acc[m][n][i] + bv);
        }
    }
}

// ---------- per-edge head computation (+ node_preds zeroing) ----------
// ag: (12544 x 1024) bf16, cols 0..511 = a, 512..1023 = g
__global__ __launch_bounds__(256) void edge_kernel(
    const u16* __restrict__ ag, const float* __restrict__ pos,
    const float* __restrict__ b1, const float* __restrict__ W2h,
    const float* __restrict__ bias7,
    float* __restrict__ edge_out, float* __restrict__ mask_out,
    float* __restrict__ node_preds) {
    __shared__ float red[4][7];
    const int e = blockIdx.x;                // 0..2047
    const int b = e >> 6, ij = e & 63, i = ij >> 3, j = ij & 7;
    const int t = threadIdx.x;
    // zero this block's slice of node_preds (2048 * 450 = 921600)
    for (int z = t; z < 450; z += 256) node_preds[(size_t)e * 450 + z] = 0.0f;
    const float dx = pos[(b * 8 + i) * 3 + 0] - pos[(b * 8 + j) * 3 + 0];
    const float dy = pos[(b * 8 + i) * 3 + 1] - pos[(b * 8 + j) * 3 + 1];
    const bool msk = (dx * dx + dy * dy < 0.25f) && (i != j);
    if (t == 0) mask_out[e] = msk ? 1.0f : 0.0f;
    if (!msk) {                              // block-uniform branch
        if (t < 7) edge_out[e * 7 + t] = 0.0f;
        return;
    }
    const int h0 = t * 2;
    const u16* arow = ag + (size_t)(b * 8 + i) * 49 * 1024 + h0;
    const u16* grow = ag + (size_t)(b * 8 + j) * 49 * 1024 + 512 + h0;
    const float b10 = b1[h0], b11 = b1[h0 + 1];
    float r0 = 0.f, r1 = 0.f;
#pragma unroll 7
    for (int s = 0; s < 49; s++) {
        u32 av = *(const u32*)(arow + (size_t)s * 1024);
        u32 gv = *(const u32*)(grow + (size_t)s * 1024);
        float a0 = bfbits2f(av << 16), a1 = bfbits2f(av & 0xFFFF0000u);
        float g0 = bfbits2f(gv << 16), g1 = bfbits2f(gv & 0xFFFF0000u);
        r0 += fmaxf(a0 + g0 + b10, 0.f);
        r1 += fmaxf(a1 + g1 + b11, 0.f);
    }
    float c[7];
#pragma unroll
    for (int k = 0; k < 7; k++)
        c[k] = r0 * W2h[h0 * 7 + k] + r1 * W2h[(h0 + 1) * 7 + k];
#pragma unroll
    for (int k = 0; k < 7; k++)
#pragma unroll
        for (int off = 32; off; off >>= 1)
            c[k] += __shfl_down(c[k], off, 64);
    const int lane = t & 63, wv = t >> 6;
    if (lane == 0)
        for (int k = 0; k < 7; k++) red[wv][k] = c[k];
    __syncthreads();
    if (t == 0)
        for (int k = 0; k < 7; k++) {
            float v = red[0][k] + red[1][k] + red[2][k] + red[3][k];
            edge_out[e * 7 + k] = v * (1.f / 49.f) + bias7[k];
        }
}

// ---------- launch ----------
extern "C" void kernel_launch(void* const* d_in, const int* in_sizes, int n_in,
                              void* d_out, int out_size, void* d_ws, size_t ws_size,
                              hipStream_t stream) {
    const float* img    = (const float*)d_in[0];
    const float* pos    = (const float*)d_in[1];
    const float* W_patch= (const float*)d_in[3];
    const float* b_patch= (const float*)d_in[4];
    const float* W1a    = (const float*)d_in[5];
    const float* W1b    = (const float*)d_in[6];
    const float* b1     = (const float*)d_in[7];
    const float* W2     = (const float*)d_in[8];
    const float* b2     = (const float*)d_in[9];
    const float* Wp     = (const float*)d_in[10];
    const float* bp     = (const float*)d_in[11];
    const float* Wpv    = (const float*)d_in[12];
    const float* bpv    = (const float*)d_in[13];
    const float* Wr     = (const float*)d_in[14];
    const float* br     = (const float*)d_in[15];
    const float* Wrv    = (const float*)d_in[16];
    const float* brv    = (const float*)d_in[17];

    char* ws = (char*)d_ws;
    u16*   patches = (u16*)(ws + 0);                      // 12544*3072*2 = 77,070,336
    u16*   ag      = (u16*)(ws + 77070336);               // 12544*1024*2 = 25,690,112
    u16*   feats   = (u16*)(ws + 102760448);              // 12544*384*2  =  9,633,792
    u16*   wpb     = (u16*)(ws + 112394240);              // 384*3072*2   =  2,359,296
    u16*   w1cat   = (u16*)(ws + 114753536);              // 1024*384*2   =    786,432
    float* W2h     = (float*)(ws + 115539968);            // 512*7*4      =     14,336
    float* bias7   = (float*)(ws + 115554304);            // 7*4

    float* edge_out   = (float*)d_out;                    // 2048*7
    float* mask_out   = edge_out + 14336;                 // 2048
    float* node_preds = mask_out + 2048;                  // 32*8*3600 = 921,600

    prep_fast<<<4832, 256, 0, stream>>>(img, patches, W_patch, wpb,
                                        W1a, W1b, w1cat,
                                        W2, b2, Wp, bp, Wpv, bpv, Wr, br, Wrv, brv,
                                        W2h, bias7);

    dim3 g1(98, 6);   // BM=128, BN=64 -> 588 blocks (~2.3/CU for barrier-drain overlap)
    gemm_bt<128, 64><<<g1, 256, 0, stream>>>(patches, wpb, feats, b_patch, 12544, 384, 3072);
    dim3 g2(196, 8);  // BM=64, BN=128 -> 1568 blocks (~6/CU, short-K GEMM)
    gemm_bt<64, 128><<<g2, 256, 0, stream>>>(feats, w1cat, ag, nullptr, 12544, 1024, 384);

    edge_kernel<<<2048, 256, 0, stream>>>(ag, pos, b1, W2h, bias7,
                                          edge_out, mask_out, node_preds);
}